// Round 3
// baseline (545.144 us; speedup 1.0000x reference)
//
#include <hip/hip_runtime.h>
#include <hip/hip_bf16.h>
#include <stdint.h>

// Problem dims (fixed by reference)
#define M_ROWS 8192   // B*S
#define K_OUT  4096   // K (output features)
#define N_RED  4096   // N (reduction dim)
#define NGRP   32

// GEMM tile (256^2, BK=64, 4 phases per K-tile, double-buffered)
#define BM 256
#define BN 256
#define BK 64
#define NKT (N_RED / BK)   // 64 K-tiles

typedef __attribute__((ext_vector_type(8))) __bf16 bf16x8;
typedef __attribute__((ext_vector_type(4))) float   f32x4;

// ---------- helpers ----------

__device__ __forceinline__ unsigned short f32_to_bf16_rn(float f) {
  uint32_t u = __float_as_uint(f);
  uint32_t r = (u + 0x7FFFu + ((u >> 16) & 1u)) >> 16;  // RNE
  return (unsigned short)r;
}

// async global -> LDS, 16 B/lane. LDS dest = wave-uniform base + lane*16;
// global src is per-lane (the layout permutation lives on the SOURCE).
__device__ __forceinline__ void async_copy16(const void* gsrc, void* lds_base) {
  __builtin_amdgcn_global_load_lds(
      (const __attribute__((address_space(1))) uint32_t*)gsrc,
      (__attribute__((address_space(3))) uint32_t*)lds_base,
      16 /*literal*/, 0, 0);
}

// ---------- kernel 1: fused prep (x->bf16, W dequant->bf16) ----------
constexpr size_t XCHUNKS = (size_t)M_ROWS * N_RED / 8;  // 4,194,304
constexpr size_t WCHUNKS = (size_t)K_OUT * N_RED / 8;   // 2,097,152

__global__ __launch_bounds__(256) void prep_kernel(
    const float* __restrict__ x, const int* __restrict__ Wq,
    const float* __restrict__ scales, const float* __restrict__ zeros,
    const float* __restrict__ mu1, const float* __restrict__ mu2,
    unsigned short* __restrict__ xb, unsigned short* __restrict__ Wb) {
  const size_t stride = (size_t)gridDim.x * 256;
  for (size_t c = (size_t)blockIdx.x * 256 + threadIdx.x;
       c < XCHUNKS + WCHUNKS; c += stride) {
    if (c < XCHUNKS) {
      const float4* xp = (const float4*)(x + c * 8);
      float4 v0 = xp[0];
      float4 v1 = xp[1];
      union { unsigned short h[8]; uint4 v; } p;
      p.h[0] = f32_to_bf16_rn(v0.x); p.h[1] = f32_to_bf16_rn(v0.y);
      p.h[2] = f32_to_bf16_rn(v0.z); p.h[3] = f32_to_bf16_rn(v0.w);
      p.h[4] = f32_to_bf16_rn(v1.x); p.h[5] = f32_to_bf16_rn(v1.y);
      p.h[6] = f32_to_bf16_rn(v1.z); p.h[7] = f32_to_bf16_rn(v1.w);
      *(uint4*)(xb + c * 8) = p.v;
    } else {
      size_t idx = c - XCHUNKS;
      int k = (int)(idx >> 9);          // 512 chunks per K-row
      int n = (int)(idx & 511) << 3;
      int g = n >> 7;
      float s  = scales[k * NGRP + g];
      float z  = zeros[k * NGRP + g];
      float sm = s * mu2[k];
      const int4* qp = (const int4*)(Wq + (size_t)k * N_RED + n);
      int4 q0 = qp[0];
      int4 q1 = qp[1];
      const float4* mp = (const float4*)(mu1 + n);
      float4 m0 = mp[0];
      float4 m1 = mp[1];
      union { unsigned short h[8]; uint4 v; } p;
      p.h[0] = f32_to_bf16_rn(((float)q0.x - z) * sm * m0.x);
      p.h[1] = f32_to_bf16_rn(((float)q0.y - z) * sm * m0.y);
      p.h[2] = f32_to_bf16_rn(((float)q0.z - z) * sm * m0.z);
      p.h[3] = f32_to_bf16_rn(((float)q0.w - z) * sm * m0.w);
      p.h[4] = f32_to_bf16_rn(((float)q1.x - z) * sm * m1.x);
      p.h[5] = f32_to_bf16_rn(((float)q1.y - z) * sm * m1.y);
      p.h[6] = f32_to_bf16_rn(((float)q1.z - z) * sm * m1.z);
      p.h[7] = f32_to_bf16_rn(((float)q1.w - z) * sm * m1.w);
      *(uint4*)(Wb + (size_t)k * N_RED + n) = p.v;
    }
  }
}

// ---------- kernel 2: 256^2 bf16 GEMM, C = A * B^T + bias ----------
// A: [8192][4096] bf16, B: [4096][4096] bf16 (K-contiguous), C fp32.
// 512 threads = 8 waves (2M x 4N); per-wave 128x64 output = 8x4 frags of
// 16x16x32 MFMA.
//
// LDS layout = FRAGMENT ORDER (conflict-free reads by construction):
// per buffer: A at 0, B at 16384 elems; each operand = 2 k-halves (kk) of
// 8192 elems; each half = 16 sub-blocks (one per 16-row group) of 512 elems;
// sub-block chunk c (16B, c=0..63) holds global (row = mi*16 + (c&15),
// k = kk*32 + ((c>>4)&3)*8 .. +8). A ds_read_b128 at lane*16 within a
// sub-block is a contiguous 1KB linear burst -> zero bank conflicts.
// global_load_lds dest stays linear (chunk index = l*512 + tid); the
// permutation is applied to the per-lane global SOURCE address.
//
// Schedule (identical sync structure to the round-2 kernel, race-screened):
// per K-tile 4 phases; stage FIFO per tile = [A.kk0 x2, B.kk0 x2,
// A.kk1 x2, B.kk1 x2]; vmcnt(4) before ph0/ph2; s_barrier + sched_barrier
// per phase; setprio(1) around each 16-MFMA cluster.
__global__ __launch_bounds__(512, 2) void gemm8_kernel(
    const unsigned short* __restrict__ A, const unsigned short* __restrict__ B,
    const float* __restrict__ bias, float* __restrict__ C) {
  __shared__ __align__(16) unsigned short lds[2][32768];  // 128 KiB

  // XCD-bijective swizzle: 512 wgs = 8 XCDs x 64 (32 tileM x 16 tileN)
  const int bid = blockIdx.x;
  const int wg = (bid & 7) * 64 + (bid >> 3);
  const int tileM = wg >> 4;   // 0..31
  const int tileN = wg & 15;   // 0..15

  const int tid  = threadIdx.x;
  const int wave = tid >> 6;
  const int lane = tid & 63;
  const int wm = wave >> 2;    // 0..1
  const int wn = wave & 3;     // 0..3
  const int fr = lane & 15;
  const int fq = lane >> 4;

  const unsigned short* Ag = A + (size_t)(tileM * BM) * N_RED;
  const unsigned short* Bg = B + (size_t)(tileN * BN) * N_RED;

  // staging source addresses: stage instr l (0,1) covers chunks f = l*512+tid
  // of a (operand, kk) half. chunk f -> row (f>>6)*16 + (f&15),
  // k-offset ((f>>4)&3)*8 within the 32-elem kk slice.
  const unsigned short* srcA[2];
  const unsigned short* srcB[2];
#pragma unroll
  for (int l = 0; l < 2; ++l) {
    int f = l * 512 + tid;
    int row = (f >> 6) * 16 + (f & 15);
    int kc8 = ((f >> 4) & 3) * 8;
    srcA[l] = Ag + (size_t)row * N_RED + kc8;
    srcB[l] = Bg + (size_t)row * N_RED + kc8;
  }

  f32x4 acc[8][4] = {};
  bf16x8 af[8], bfr[2];

  // stage one (operand, kk) group: 2 async copies
#define STAGE_A(nb, kk)                                                       \
  do {                                                                        \
    async_copy16(srcA[0] + (kk) * 32, &lds[nb][(kk) * 8192 + wave * 512]);    \
    async_copy16(srcA[1] + (kk) * 32,                                         \
                 &lds[nb][(kk) * 8192 + 4096 + wave * 512]);                  \
  } while (0)
#define STAGE_B(nb, kk)                                                       \
  do {                                                                        \
    async_copy16(srcB[0] + (kk) * 32,                                         \
                 &lds[nb][16384 + (kk) * 8192 + wave * 512]);                 \
    async_copy16(srcB[1] + (kk) * 32,                                         \
                 &lds[nb][16384 + (kk) * 8192 + 4096 + wave * 512]);          \
  } while (0)

#define READ_A(cb, kk)                                                        \
  do {                                                                        \
    _Pragma("unroll") for (int m = 0; m < 8; ++m) af[m] =                     \
        *(const bf16x8*)&lds[cb][(kk) * 8192 + (wm * 8 + m) * 512 + lane * 8];\
  } while (0)

#define READ_B(cb, kk, nh)                                                    \
  do {                                                                        \
    bfr[0] = *(const bf16x8*)&lds[cb][16384 + (kk) * 8192 +                   \
                                      (wn * 4 + (nh) * 2) * 512 + lane * 8];  \
    bfr[1] = *(const bf16x8*)&lds[cb][16384 + (kk) * 8192 +                   \
                                      (wn * 4 + (nh) * 2 + 1) * 512 +         \
                                      lane * 8];                              \
  } while (0)

#define MFMA_BLK(nh)                                                          \
  do {                                                                        \
    __builtin_amdgcn_s_setprio(1);                                            \
    _Pragma("unroll") for (int m = 0; m < 8; ++m) {                           \
      acc[m][(nh) * 2] = __builtin_amdgcn_mfma_f32_16x16x32_bf16(             \
          af[m], bfr[0], acc[m][(nh) * 2], 0, 0, 0);                          \
      acc[m][(nh) * 2 + 1] = __builtin_amdgcn_mfma_f32_16x16x32_bf16(         \
          af[m], bfr[1], acc[m][(nh) * 2 + 1], 0, 0, 0);                      \
    }                                                                         \
    __builtin_amdgcn_s_setprio(0);                                            \
  } while (0)

  // prologue: stage tile 0 into buf 0 (FIFO: Akk0,Akk0,Bkk0,Bkk0,Akk1,...)
  STAGE_A(0, 0);
  STAGE_B(0, 0);
  STAGE_A(0, 1);
  STAGE_B(0, 1);
  srcA[0] += BK; srcA[1] += BK; srcB[0] += BK; srcB[1] += BK;

  // main loop: compute tile t from buf[t&1], stage tile t+1 into buf[t&1^1].
  for (int t = 0; t < NKT - 1; ++t) {
    const int cb = t & 1, nb = cb ^ 1;
    // ph0: kk0, n-half 0  (needs tile t's Akk0+Bkk0 = oldest 4 of 8)
    asm volatile("s_waitcnt vmcnt(4)" ::: "memory");
    __builtin_amdgcn_s_barrier();
    __builtin_amdgcn_sched_barrier(0);
    READ_A(cb, 0);
    READ_B(cb, 0, 0);
    STAGE_A(nb, 0);
    MFMA_BLK(0);
    // ph1: kk0, n-half 1
    __builtin_amdgcn_s_barrier();
    __builtin_amdgcn_sched_barrier(0);
    READ_B(cb, 0, 1);
    STAGE_B(nb, 0);
    MFMA_BLK(1);
    // ph2: kk1, n-half 0  (needs tile t's Akk1+Bkk1 = oldest 4 of 8)
    asm volatile("s_waitcnt vmcnt(4)" ::: "memory");
    __builtin_amdgcn_s_barrier();
    __builtin_amdgcn_sched_barrier(0);
    READ_A(cb, 1);
    READ_B(cb, 1, 0);
    STAGE_A(nb, 1);
    MFMA_BLK(0);
    // ph3: kk1, n-half 1
    __builtin_amdgcn_s_barrier();
    __builtin_amdgcn_sched_barrier(0);
    READ_B(cb, 1, 1);
    STAGE_B(nb, 1);
    MFMA_BLK(1);
    srcA[0] += BK; srcA[1] += BK; srcB[0] += BK; srcB[1] += BK;
  }
  // final tile (no staging; outstanding 8 -> 4 -> 0)
  {
    const int cb = (NKT - 1) & 1;
    asm volatile("s_waitcnt vmcnt(4)" ::: "memory");
    __builtin_amdgcn_s_barrier();
    __builtin_amdgcn_sched_barrier(0);
    READ_A(cb, 0); READ_B(cb, 0, 0); MFMA_BLK(0);
    __builtin_amdgcn_s_barrier();
    __builtin_amdgcn_sched_barrier(0);
    READ_B(cb, 0, 1); MFMA_BLK(1);
    asm volatile("s_waitcnt vmcnt(0)" ::: "memory");
    __builtin_amdgcn_s_barrier();
    __builtin_amdgcn_sched_barrier(0);
    READ_A(cb, 1); READ_B(cb, 1, 0); MFMA_BLK(0);
    __builtin_amdgcn_s_barrier();
    __builtin_amdgcn_sched_barrier(0);
    READ_B(cb, 1, 1); MFMA_BLK(1);
  }

  // epilogue: C/D layout col=lane&15, row=(lane>>4)*4+reg (m89/m91)
  float bv[4];
#pragma unroll
  for (int n = 0; n < 4; ++n)
    bv[n] = bias[tileN * BN + wn * 64 + n * 16 + fr];
#pragma unroll
  for (int m = 0; m < 8; ++m) {
    int row0 = tileM * BM + wm * 128 + m * 16 + fq * 4;
#pragma unroll
    for (int j = 0; j < 4; ++j) {
      float* crow = C + (size_t)(row0 + j) * K_OUT + tileN * BN + wn * 64 + fr;
#pragma unroll
      for (int n = 0; n < 4; ++n)
        crow[n * 16] = acc[m][n][j] + bv[n];
    }
  }
#undef STAGE_A
#undef STAGE_B
#undef READ_A
#undef READ_B
#undef MFMA_BLK
}

// ---------- launch ----------
extern "C" void kernel_launch(void* const* d_in, const int* in_sizes, int n_in,
                              void* d_out, int out_size, void* d_ws, size_t ws_size,
                              hipStream_t stream) {
  const float* x      = (const float*)d_in[0];
  const int*   Wq     = (const int*)d_in[1];
  const float* scales = (const float*)d_in[2];
  const float* zeros  = (const float*)d_in[3];
  const float* mu1    = (const float*)d_in[4];
  const float* mu2    = (const float*)d_in[5];
  const float* bias   = (const float*)d_in[6];
  float* out = (float*)d_out;

  unsigned short* xb = (unsigned short*)d_ws;                                 // 64 MiB
  unsigned short* Wb = (unsigned short*)((char*)d_ws +
                         (size_t)M_ROWS * N_RED * sizeof(unsigned short));    // +32 MiB

  prep_kernel<<<2048, 256, 0, stream>>>(x, Wq, scales, zeros, mu1, mu2, xb, Wb);
  gemm8_kernel<<<(M_ROWS / BM) * (K_OUT / BN), 512, 0, stream>>>(xb, Wb, bias, out);
}

// Round 5
// 524.575 us; speedup vs baseline: 1.0392x; 1.0392x over previous
//
#include <hip/hip_runtime.h>
#include <hip/hip_bf16.h>
#include <stdint.h>

// Problem dims (fixed by reference)
#define M_ROWS 8192   // B*S
#define K_OUT  4096   // K (output features)
#define N_RED  4096   // N (reduction dim)
#define NGRP   32

// GEMM tile (256^2, BK=64 as 2 kk-slices, 4 two-barrier phases per K-tile)
#define BM 256
#define BN 256
#define BK 64
#define NKT (N_RED / BK)   // 64 K-tiles

typedef __attribute__((ext_vector_type(8))) __bf16 bf16x8;
typedef __attribute__((ext_vector_type(4))) float   f32x4;

// ---------- helpers ----------

__device__ __forceinline__ unsigned short f32_to_bf16_rn(float f) {
  uint32_t u = __float_as_uint(f);
  uint32_t r = (u + 0x7FFFu + ((u >> 16) & 1u)) >> 16;  // RNE
  return (unsigned short)r;
}

// async global -> LDS, 16 B/lane. LDS dest = wave-uniform base + lane*16;
// global src is per-lane (swizzle lives on the SOURCE address; keep 64B
// lane-adjacent runs for the VMEM coalescer — round-3 lesson).
__device__ __forceinline__ void async_copy16(const void* gsrc, void* lds_base) {
  __builtin_amdgcn_global_load_lds(
      (const __attribute__((address_space(1))) uint32_t*)gsrc,
      (__attribute__((address_space(3))) uint32_t*)lds_base,
      16 /*literal*/, 0, 0);
}

// ---------- kernel 1: fused prep (x->bf16, W dequant->bf16) ----------
constexpr size_t XCHUNKS = (size_t)M_ROWS * N_RED / 8;  // 4,194,304
constexpr size_t WCHUNKS = (size_t)K_OUT * N_RED / 8;   // 2,097,152

__global__ __launch_bounds__(256) void prep_kernel(
    const float* __restrict__ x, const int* __restrict__ Wq,
    const float* __restrict__ scales, const float* __restrict__ zeros,
    const float* __restrict__ mu1, const float* __restrict__ mu2,
    unsigned short* __restrict__ xb, unsigned short* __restrict__ Wb) {
  const size_t stride = (size_t)gridDim.x * 256;
  for (size_t c = (size_t)blockIdx.x * 256 + threadIdx.x;
       c < XCHUNKS + WCHUNKS; c += stride) {
    if (c < XCHUNKS) {
      const float4* xp = (const float4*)(x + c * 8);
      float4 v0 = xp[0];
      float4 v1 = xp[1];
      union { unsigned short h[8]; uint4 v; } p;
      p.h[0] = f32_to_bf16_rn(v0.x); p.h[1] = f32_to_bf16_rn(v0.y);
      p.h[2] = f32_to_bf16_rn(v0.z); p.h[3] = f32_to_bf16_rn(v0.w);
      p.h[4] = f32_to_bf16_rn(v1.x); p.h[5] = f32_to_bf16_rn(v1.y);
      p.h[6] = f32_to_bf16_rn(v1.z); p.h[7] = f32_to_bf16_rn(v1.w);
      *(uint4*)(xb + c * 8) = p.v;
    } else {
      size_t idx = c - XCHUNKS;
      int k = (int)(idx >> 9);          // 512 chunks per K-row
      int n = (int)(idx & 511) << 3;
      int g = n >> 7;
      float s  = scales[k * NGRP + g];
      float z  = zeros[k * NGRP + g];
      float sm = s * mu2[k];
      const int4* qp = (const int4*)(Wq + (size_t)k * N_RED + n);
      int4 q0 = qp[0];
      int4 q1 = qp[1];
      const float4* mp = (const float4*)(mu1 + n);
      float4 m0 = mp[0];
      float4 m1 = mp[1];
      union { unsigned short h[8]; uint4 v; } p;
      p.h[0] = f32_to_bf16_rn(((float)q0.x - z) * sm * m0.x);
      p.h[1] = f32_to_bf16_rn(((float)q0.y - z) * sm * m0.y);
      p.h[2] = f32_to_bf16_rn(((float)q0.z - z) * sm * m0.z);
      p.h[3] = f32_to_bf16_rn(((float)q0.w - z) * sm * m0.w);
      p.h[4] = f32_to_bf16_rn(((float)q1.x - z) * sm * m1.x);
      p.h[5] = f32_to_bf16_rn(((float)q1.y - z) * sm * m1.y);
      p.h[6] = f32_to_bf16_rn(((float)q1.z - z) * sm * m1.z);
      p.h[7] = f32_to_bf16_rn(((float)q1.w - z) * sm * m1.w);
      *(uint4*)(Wb + (size_t)k * N_RED + n) = p.v;
    }
  }
}

// ---------- kernel 2: 256^2 bf16 GEMM, C = A * B^T + bias ----------
// Round-2 addressing (row-major [256][32] halves, 64B rows, XOR swizzle on
// byte bits 4,5 keyed by row bits 2,3; stage source inverse-swizzled,
// 4-lane 64B runs) + m201 two-barrier phase schedule:
//   per phase: reads -> stage 1 group -> s_barrier -> lgkmcnt(0) ->
//              setprio(1) -> 16 MFMA -> setprio(0) -> [vmcnt(4)] -> s_barrier
// Phase quadrant = (kk, m-half). Stage FIFO per tile: Akk0,Bkk0,Akk1,Bkk1
// (2 loads each); vmcnt(4) before ph1/ph3 closing barrier drains exactly the
// two groups the following phases read.
__global__ __launch_bounds__(512, 2) void gemm8_kernel(
    const unsigned short* __restrict__ A, const unsigned short* __restrict__ B,
    const float* __restrict__ bias, float* __restrict__ C) {
  __shared__ __align__(16) unsigned short lds[2][4][8192];  // 128 KiB
  // halves: h0=A.kk0, h1=B.kk0, h2=A.kk1, h3=B.kk1 ([256 rows][32 elems])

  // XCD-bijective swizzle: 512 wgs = 8 XCDs x 64 (32 tileM x 16 tileN)
  const int bid = blockIdx.x;
  const int wg = (bid & 7) * 64 + (bid >> 3);
  const int tileM = wg >> 4;   // 0..31
  const int tileN = wg & 15;   // 0..15

  const int tid  = threadIdx.x;
  const int wave = tid >> 6;
  const int lane = tid & 63;
  const int wm = wave >> 2;    // 0..1
  const int wn = wave & 3;     // 0..3
  const int fr = lane & 15;
  const int fq = lane >> 4;

  // swizzled per-lane ds_read offset within a half (bytes):
  const int laneoff =
      (fr * 64 + fq * 16) ^ ((fr & 8) << 2) ^ ((fr & 4) << 2);

  // staging source addresses (inverse-swizzled global, 64B runs kept)
  const unsigned short* srcA[2];
  const unsigned short* srcB[2];
#pragma unroll
  for (int l = 0; l < 2; ++l) {
    int a = (l * 512 + tid) * 16;  // linear dest byte within half
    int q = a ^ (((a >> 9) & 1) << 5) ^ (((a >> 8) & 1) << 4);
    int row = q >> 6;
    int ce  = (q & 63) >> 1;
    srcA[l] = A + (size_t)(tileM * BM + row) * N_RED + ce;
    srcB[l] = B + (size_t)(tileN * BN + row) * N_RED + ce;
  }
  const int dst0 = wave * 512;          // elems (lane*16B added by HW)
  const int dst1 = 4096 + wave * 512;

  f32x4 acc[8][4] = {};
  bf16x8 af[4], bfr[4];

#define STAGE_A(nb, kk)                                                       \
  do {                                                                        \
    async_copy16(srcA[0] + (kk) * 32, &lds[nb][(kk) * 2][dst0]);              \
    async_copy16(srcA[1] + (kk) * 32, &lds[nb][(kk) * 2][dst1]);              \
  } while (0)
#define STAGE_B(nb, kk)                                                       \
  do {                                                                        \
    async_copy16(srcB[0] + (kk) * 32, &lds[nb][(kk) * 2 + 1][dst0]);          \
    async_copy16(srcB[1] + (kk) * 32, &lds[nb][(kk) * 2 + 1][dst1]);          \
  } while (0)

  // A: 4 frags for m-half mh (rows wm*128 + mh*64 + m*16 + fr)
#define READ_A4(cb, kk, mh)                                                   \
  do {                                                                        \
    const char* ab = (const char*)&lds[cb][(kk) * 2][0] + wm * 8192 +         \
                     (mh) * 4096 + laneoff;                                   \
    _Pragma("unroll") for (int m = 0; m < 4; ++m)                             \
        af[m] = *(const bf16x8*)(ab + m * 1024);                              \
  } while (0)
  // B: all 4 n-frags for this kk (rows wn*64 + n*16 + fr)
#define READ_B4(cb, kk)                                                       \
  do {                                                                        \
    const char* bb_ = (const char*)&lds[cb][(kk) * 2 + 1][0] + wn * 4096 +    \
                      laneoff;                                                \
    _Pragma("unroll") for (int n = 0; n < 4; ++n)                             \
        bfr[n] = *(const bf16x8*)(bb_ + n * 1024);                            \
  } while (0)

#define MFMA16(mh)                                                            \
  do {                                                                        \
    __builtin_amdgcn_s_setprio(1);                                            \
    _Pragma("unroll") for (int m = 0; m < 4; ++m)                             \
        _Pragma("unroll") for (int n = 0; n < 4; ++n)                         \
            acc[(mh) * 4 + m][n] = __builtin_amdgcn_mfma_f32_16x16x32_bf16(   \
                af[m], bfr[n], acc[(mh) * 4 + m][n], 0, 0, 0);                \
    __builtin_amdgcn_s_setprio(0);                                            \
  } while (0)

#define BAR()   __builtin_amdgcn_s_barrier()
#define SBAR()  __builtin_amdgcn_sched_barrier(0)
#define LGKM0() asm volatile("s_waitcnt lgkmcnt(0)" ::: "memory")
#define VM(n)   asm volatile("s_waitcnt vmcnt(" #n ")" ::: "memory")

  // prologue: stage tile 0 (FIFO: Akk0, Bkk0, Akk1, Bkk1 = 8 loads)
  STAGE_A(0, 0);
  STAGE_B(0, 0);
  STAGE_A(0, 1);
  STAGE_B(0, 1);
  srcA[0] += BK; srcA[1] += BK; srcB[0] += BK; srcB[1] += BK;
  VM(4);   // Akk0+Bkk0 landed
  BAR();
  SBAR();

  for (int t = 0; t < NKT - 1; ++t) {
    const int cb = t & 1, nb = cb ^ 1;
    // ph0: kk0, m-half 0 | stage Akk0(t+1)
    READ_A4(cb, 0, 0); READ_B4(cb, 0); STAGE_A(nb, 0);
    BAR(); LGKM0(); SBAR();
    MFMA16(0);
    BAR(); SBAR();
    // ph1: kk0, m-half 1 | stage Bkk0(t+1) | vmcnt(4) -> kk1(t) ready
    READ_A4(cb, 0, 1); STAGE_B(nb, 0);
    BAR(); LGKM0(); SBAR();
    MFMA16(1);
    VM(4); BAR(); SBAR();
    // ph2: kk1, m-half 0 | stage Akk1(t+1)
    READ_A4(cb, 1, 0); READ_B4(cb, 1); STAGE_A(nb, 1);
    BAR(); LGKM0(); SBAR();
    MFMA16(0);
    BAR(); SBAR();
    // ph3: kk1, m-half 1 | stage Bkk1(t+1) | vmcnt(4) -> kk0(t+1) ready
    READ_A4(cb, 1, 1); STAGE_B(nb, 1);
    BAR(); LGKM0(); SBAR();
    MFMA16(1);
    VM(4); BAR(); SBAR();
    srcA[0] += BK; srcA[1] += BK; srcB[0] += BK; srcB[1] += BK;
  }
  // tail tile (no staging; outstanding 4 -> 0)
  {
    const int cb = (NKT - 1) & 1;
    READ_A4(cb, 0, 0); READ_B4(cb, 0);
    BAR(); LGKM0(); SBAR();
    MFMA16(0);
    BAR(); SBAR();
    READ_A4(cb, 0, 1);
    BAR(); LGKM0(); SBAR();
    MFMA16(1);
    VM(0); BAR(); SBAR();
    READ_A4(cb, 1, 0); READ_B4(cb, 1);
    BAR(); LGKM0(); SBAR();
    MFMA16(0);
    BAR(); SBAR();
    READ_A4(cb, 1, 1);
    BAR(); LGKM0(); SBAR();
    MFMA16(1);
  }

  // epilogue: C/D layout col=lane&15, row=(lane>>4)*4+reg (m89/m91)
  float bv[4];
#pragma unroll
  for (int n = 0; n < 4; ++n)
    bv[n] = bias[tileN * BN + wn * 64 + n * 16 + fr];
#pragma unroll
  for (int m = 0; m < 8; ++m) {
    int row0 = tileM * BM + wm * 128 + m * 16 + fq * 4;
#pragma unroll
    for (int j = 0; j < 4; ++j) {
      float* crow = C + (size_t)(row0 + j) * K_OUT + tileN * BN + wn * 64 + fr;
#pragma unroll
      for (int n = 0; n < 4; ++n)
        crow[n * 16] = acc[m][n][j] + bv[n];
    }
  }
#undef STAGE_A
#undef STAGE_B
#undef READ_A4
#undef READ_B4
#undef MFMA16
#undef BAR
#undef SBAR
#undef LGKM0
#undef VM
}

// ---------- launch ----------
extern "C" void kernel_launch(void* const* d_in, const int* in_sizes, int n_in,
                              void* d_out, int out_size, void* d_ws, size_t ws_size,
                              hipStream_t stream) {
  const float* x      = (const float*)d_in[0];
  const int*   Wq     = (const int*)d_in[1];
  const float* scales = (const float*)d_in[2];
  const float* zeros  = (const float*)d_in[3];
  const float* mu1    = (const float*)d_in[4];
  const float* mu2    = (const float*)d_in[5];
  const float* bias   = (const float*)d_in[6];
  float* out = (float*)d_out;

  unsigned short* xb = (unsigned short*)d_ws;                                 // 64 MiB
  unsigned short* Wb = (unsigned short*)((char*)d_ws +
                         (size_t)M_ROWS * N_RED * sizeof(unsigned short));    // +32 MiB

  prep_kernel<<<2048, 256, 0, stream>>>(x, Wq, scales, zeros, mu1, mu2, xb, Wb);
  gemm8_kernel<<<(M_ROWS / BM) * (K_OUT / BN), 512, 0, stream>>>(xb, Wb, bias, out);
}

// Round 8
// 502.725 us; speedup vs baseline: 1.0844x; 1.0435x over previous
//
#include <hip/hip_runtime.h>
#include <hip/hip_bf16.h>
#include <stdint.h>

// Problem dims (fixed by reference)
#define M_ROWS 8192   // B*S
#define K_OUT  4096   // K (output features)
#define N_RED  4096   // N (reduction dim)
#define NGRP   32

// GEMM tile (256^2 template, BK=64, 4 single-barrier phases per K-tile)
#define BM 256
#define BN 256
#define BK 64
#define NKT (N_RED / BK)   // 64 K-tiles

typedef __attribute__((ext_vector_type(8))) __bf16 bf16x8;
typedef __attribute__((ext_vector_type(4))) float   f32x4;

// ---------- helpers ----------

__device__ __forceinline__ unsigned short f32_to_bf16_rn(float f) {
  uint32_t u = __float_as_uint(f);
  uint32_t r = (u + 0x7FFFu + ((u >> 16) & 1u)) >> 16;  // RNE
  return (unsigned short)r;
}

// async global -> LDS, 16 B/lane. LDS dest = wave-uniform base + lane*16;
// global src is per-lane (swizzle lives on the SOURCE address; keep 64B
// lane-adjacent runs for the VMEM coalescer — round-3 lesson).
__device__ __forceinline__ void async_copy16(const void* gsrc, void* lds_base) {
  __builtin_amdgcn_global_load_lds(
      (const __attribute__((address_space(1))) uint32_t*)gsrc,
      (__attribute__((address_space(3))) uint32_t*)lds_base,
      16 /*literal*/, 0, 0);
}

// ---------- kernel 1: fused prep (x->bf16, W dequant->bf16) ----------
constexpr size_t XCHUNKS = (size_t)M_ROWS * N_RED / 8;  // 4,194,304
constexpr size_t WCHUNKS = (size_t)K_OUT * N_RED / 8;   // 2,097,152

__global__ __launch_bounds__(256) void prep_kernel(
    const float* __restrict__ x, const int* __restrict__ Wq,
    const float* __restrict__ scales, const float* __restrict__ zeros,
    const float* __restrict__ mu1, const float* __restrict__ mu2,
    unsigned short* __restrict__ xb, unsigned short* __restrict__ Wb) {
  const size_t stride = (size_t)gridDim.x * 256;
  for (size_t c = (size_t)blockIdx.x * 256 + threadIdx.x;
       c < XCHUNKS + WCHUNKS; c += stride) {
    if (c < XCHUNKS) {
      const float4* xp = (const float4*)(x + c * 8);
      float4 v0 = xp[0];
      float4 v1 = xp[1];
      union { unsigned short h[8]; uint4 v; } p;
      p.h[0] = f32_to_bf16_rn(v0.x); p.h[1] = f32_to_bf16_rn(v0.y);
      p.h[2] = f32_to_bf16_rn(v0.z); p.h[3] = f32_to_bf16_rn(v0.w);
      p.h[4] = f32_to_bf16_rn(v1.x); p.h[5] = f32_to_bf16_rn(v1.y);
      p.h[6] = f32_to_bf16_rn(v1.z); p.h[7] = f32_to_bf16_rn(v1.w);
      *(uint4*)(xb + c * 8) = p.v;
    } else {
      size_t idx = c - XCHUNKS;
      int k = (int)(idx >> 9);          // 512 chunks per K-row
      int n = (int)(idx & 511) << 3;
      int g = n >> 7;
      float s  = scales[k * NGRP + g];
      float z  = zeros[k * NGRP + g];
      float sm = s * mu2[k];
      const int4* qp = (const int4*)(Wq + (size_t)k * N_RED + n);
      int4 q0 = qp[0];
      int4 q1 = qp[1];
      const float4* mp = (const float4*)(mu1 + n);
      float4 m0 = mp[0];
      float4 m1 = mp[1];
      union { unsigned short h[8]; uint4 v; } p;
      p.h[0] = f32_to_bf16_rn(((float)q0.x - z) * sm * m0.x);
      p.h[1] = f32_to_bf16_rn(((float)q0.y - z) * sm * m0.y);
      p.h[2] = f32_to_bf16_rn(((float)q0.z - z) * sm * m0.z);
      p.h[3] = f32_to_bf16_rn(((float)q0.w - z) * sm * m0.w);
      p.h[4] = f32_to_bf16_rn(((float)q1.x - z) * sm * m1.x);
      p.h[5] = f32_to_bf16_rn(((float)q1.y - z) * sm * m1.y);
      p.h[6] = f32_to_bf16_rn(((float)q1.z - z) * sm * m1.z);
      p.h[7] = f32_to_bf16_rn(((float)q1.w - z) * sm * m1.w);
      *(uint4*)(Wb + (size_t)k * N_RED + n) = p.v;
    }
  }
}

// ---------- kernel 2: 256^2 bf16 GEMM, C = A * B^T + bias ----------
// EXACT round-2 schedule (best measured: 257 µs): 4 single-barrier phases
// per K-tile, counted vmcnt(4) at ph0/ph2, stage interleaved with MFMA,
// setprio(1) around MFMA clusters.
// ONLY change vs round 2: the LDS XOR-swizzle key. Bank-base bits of a
// ds_read_b128 lane are byte bits {4,5,6} = {fq0,fq1,fr0}. XORing bits 4,5
// with fr1,fr2 (instead of fr2,fr3) makes (fr0,fr1,fr2) -> 8 distinct
// bank-bases within every 8-lane service group -> conflict-free reads.
// Staging source uses the same involution (stored-addr bits 4,5 ^= bits 7,8),
// confined within 64B -> 4-lane coalesced runs preserved.
__global__ __launch_bounds__(512, 2) void gemm8_kernel(
    const unsigned short* __restrict__ A, const unsigned short* __restrict__ B,
    const float* __restrict__ bias, float* __restrict__ C) {
  __shared__ __align__(16) unsigned short lds[2][4][8192];  // 128 KiB
  // halves: h0=A.kk0, h1=B.kk0, h2=A.kk1, h3=B.kk1 ([256 rows][32 elems])

  // XCD-bijective swizzle: 512 wgs = 8 XCDs x 64 (32 tileM x 16 tileN)
  const int bid = blockIdx.x;
  const int wg = (bid & 7) * 64 + (bid >> 3);
  const int tileM = wg >> 4;   // 0..31
  const int tileN = wg & 15;   // 0..15

  const int tid  = threadIdx.x;
  const int wave = tid >> 6;
  const int lane = tid & 63;
  const int wm = wave >> 2;    // 0..1
  const int wn = wave & 3;     // 0..3
  const int fr = lane & 15;
  const int fq = lane >> 4;

  // swizzled per-lane ds_read offset within a half (bytes):
  // bits 4,5 ^= fr1,fr2   (conflict-free key)
  const int laneoff =
      (fr * 64 + fq * 16) ^ ((fr & 2) << 3) ^ ((fr & 4) << 3);

  // staging source addresses (inverse-swizzled global, 64B runs kept):
  // stored byte a holds logical byte a ^ ((a7)<<4) ^ ((a8)<<5)
  const unsigned short* srcA[2];
  const unsigned short* srcB[2];
#pragma unroll
  for (int l = 0; l < 2; ++l) {
    int a = (l * 512 + tid) * 16;  // linear dest byte within half
    int q = a ^ (((a >> 7) & 1) << 4) ^ (((a >> 8) & 1) << 5);
    int row = q >> 6;
    int ce  = (q & 63) >> 1;
    srcA[l] = A + (size_t)(tileM * BM + row) * N_RED + ce;
    srcB[l] = B + (size_t)(tileN * BN + row) * N_RED + ce;
  }
  const int dst0 = wave * 512;          // elems (lane*16B added by HW)
  const int dst1 = 4096 + wave * 512;

  f32x4 acc[8][4] = {};
  bf16x8 af[8], bfr[2];

#define STAGE(nb, h)                                                         \
  do {                                                                       \
    async_copy16(((h) & 1 ? srcB : srcA)[0] + ((h) >> 1) * 32,               \
                 &lds[nb][h][dst0]);                                         \
    async_copy16(((h) & 1 ? srcB : srcA)[1] + ((h) >> 1) * 32,               \
                 &lds[nb][h][dst1]);                                         \
  } while (0)

#define READ_A(cb, ks)                                                       \
  do {                                                                       \
    const char* ab =                                                         \
        (const char*)&lds[cb][(ks) * 2][0] + wm * 8192 + laneoff;            \
    _Pragma("unroll") for (int m = 0; m < 8; ++m)                            \
        af[m] = *(const bf16x8*)(ab + m * 1024);                             \
  } while (0)

#define READ_B(cb, ks, nh)                                                   \
  do {                                                                       \
    const char* bb_ = (const char*)&lds[cb][(ks) * 2 + 1][0] + wn * 4096 +   \
                      laneoff + (nh) * 2048;                                 \
    bfr[0] = *(const bf16x8*)(bb_);                                          \
    bfr[1] = *(const bf16x8*)(bb_ + 1024);                                   \
  } while (0)

#define MFMA_BLK(nh)                                                         \
  do {                                                                       \
    __builtin_amdgcn_s_setprio(1);                                           \
    _Pragma("unroll") for (int m = 0; m < 8; ++m) {                          \
      acc[m][(nh) * 2] = __builtin_amdgcn_mfma_f32_16x16x32_bf16(            \
          af[m], bfr[0], acc[m][(nh) * 2], 0, 0, 0);                         \
      acc[m][(nh) * 2 + 1] = __builtin_amdgcn_mfma_f32_16x16x32_bf16(        \
          af[m], bfr[1], acc[m][(nh) * 2 + 1], 0, 0, 0);                     \
    }                                                                        \
    __builtin_amdgcn_s_setprio(0);                                           \
  } while (0)

  // prologue: stage tile 0 into buf 0 (8 loads outstanding)
#pragma unroll
  for (int h = 0; h < 4; ++h) STAGE(0, h);
  srcA[0] += BK; srcA[1] += BK; srcB[0] += BK; srcB[1] += BK;

  // main loop: compute tile t from buf[t&1], stage tile t+1 into buf[~t&1].
  // vmcnt(4) at ph0/ph2 drains exactly the two halves about to be read.
  for (int t = 0; t < NKT - 1; ++t) {
    const int cb = t & 1, nb = cb ^ 1;
    // ph0: ks0, n-half 0
    asm volatile("s_waitcnt vmcnt(4)" ::: "memory");
    __builtin_amdgcn_s_barrier();
    __builtin_amdgcn_sched_barrier(0);
    READ_A(cb, 0);
    READ_B(cb, 0, 0);
    STAGE(nb, 0);
    MFMA_BLK(0);
    // ph1: ks0, n-half 1
    __builtin_amdgcn_s_barrier();
    __builtin_amdgcn_sched_barrier(0);
    READ_B(cb, 0, 1);
    STAGE(nb, 1);
    MFMA_BLK(1);
    // ph2: ks1, n-half 0
    asm volatile("s_waitcnt vmcnt(4)" ::: "memory");
    __builtin_amdgcn_s_barrier();
    __builtin_amdgcn_sched_barrier(0);
    READ_A(cb, 1);
    READ_B(cb, 1, 0);
    STAGE(nb, 2);
    MFMA_BLK(0);
    // ph3: ks1, n-half 1
    __builtin_amdgcn_s_barrier();
    __builtin_amdgcn_sched_barrier(0);
    READ_B(cb, 1, 1);
    STAGE(nb, 3);
    MFMA_BLK(1);
    srcA[0] += BK; srcA[1] += BK; srcB[0] += BK; srcB[1] += BK;
  }
  // final tile (no staging; drain 4 -> 0)
  {
    const int cb = (NKT - 1) & 1;
    asm volatile("s_waitcnt vmcnt(4)" ::: "memory");
    __builtin_amdgcn_s_barrier();
    __builtin_amdgcn_sched_barrier(0);
    READ_A(cb, 0); READ_B(cb, 0, 0); MFMA_BLK(0);
    __builtin_amdgcn_s_barrier();
    __builtin_amdgcn_sched_barrier(0);
    READ_B(cb, 0, 1); MFMA_BLK(1);
    asm volatile("s_waitcnt vmcnt(0)" ::: "memory");
    __builtin_amdgcn_s_barrier();
    __builtin_amdgcn_sched_barrier(0);
    READ_A(cb, 1); READ_B(cb, 1, 0); MFMA_BLK(0);
    __builtin_amdgcn_s_barrier();
    __builtin_amdgcn_sched_barrier(0);
    READ_B(cb, 1, 1); MFMA_BLK(1);
  }

  // epilogue: C/D layout col=lane&15, row=(lane>>4)*4+reg (m89/m91)
  float bv[4];
#pragma unroll
  for (int n = 0; n < 4; ++n)
    bv[n] = bias[tileN * BN + wn * 64 + n * 16 + fr];
#pragma unroll
  for (int m = 0; m < 8; ++m) {
    int row0 = tileM * BM + wm * 128 + m * 16 + fq * 4;
#pragma unroll
    for (int j = 0; j < 4; ++j) {
      float* crow = C + (size_t)(row0 + j) * K_OUT + tileN * BN + wn * 64 + fr;
#pragma unroll
      for (int n = 0; n < 4; ++n)
        crow[n * 16] = acc[m][n][j] + bv[n];
    }
  }
#undef STAGE
#undef READ_A
#undef READ_B
#undef MFMA_BLK
}

// ---------- launch ----------
extern "C" void kernel_launch(void* const* d_in, const int* in_sizes, int n_in,
                              void* d_out, int out_size, void* d_ws, size_t ws_size,
                              hipStream_t stream) {
  const float* x      = (const float*)d_in[0];
  const int*   Wq     = (const int*)d_in[1];
  const float* scales = (const float*)d_in[2];
  const float* zeros  = (const float*)d_in[3];
  const float* mu1    = (const float*)d_in[4];
  const float* mu2    = (const float*)d_in[5];
  const float* bias   = (const float*)d_in[6];
  float* out = (float*)d_out;

  unsigned short* xb = (unsigned short*)d_ws;                                 // 64 MiB
  unsigned short* Wb = (unsigned short*)((char*)d_ws +
                         (size_t)M_ROWS * N_RED * sizeof(unsigned short));    // +32 MiB

  prep_kernel<<<2048, 256, 0, stream>>>(x, Wq, scales, zeros, mu1, mu2, xb, Wb);
  gemm8_kernel<<<(M_ROWS / BM) * (K_OUT / BN), 512, 0, stream>>>(xb, Wb, bias, out);
}